// Round 5
// baseline (523.983 us; speedup 1.0000x reference)
//
#include <hip/hip_runtime.h>
#include <math.h>

#define NNZ_C 3200000
#define NN_C  100000
#define NE_C  100000
#define KD    16
#define EPSF  1e-6f
#define LSEP  0.1f

#define NBKT  400          // buckets
#define BEDG  250          // edges per bucket (NBKT*BEDG = NE_C)
#define RCAP  8704         // record capacity per bucket (mean 8000, +8 sigma)
#define SLICES 2           // scan blocks per bucket

typedef unsigned int uint_t;

// ---------- workspace layout (word offsets), total ~34.1 MB ----------
//   [0, 50000)            packed degree counters (u32, 4x8-bit bins)   (zeroed)
//   [50000, 50512)        bucket cursors (NBKT used)                   (zeroed)
//   [50512, 50576)        acc: theta[0..15], fdvf[16..31], sep[32..35] (zeroed)
//   [50576, +100000)      Dv (fully written by k_unpack)
//   [150576, +100000)     De (fully written by k_unpack)
//   [250576, +1600000)    nZ (fully written by k_norm)
//   [1850576, +NBKT*RCAP) bucket records u32
//   [5332176, +NBKT*SLICES*BEDG*KD) S slice partials (fully written)
#define W_PK    0
#define W_CUR   50000
#define W_ACC   50512
#define W_DV    50576
#define W_DE    150576
#define W_NZ    250576
#define W_REC   1850576
#define W_PART  (W_REC + NBKT * RCAP)
#define W_END   (W_PART + NBKT * SLICES * BEDG * KD)
#define W_ZERO  W_DV

// ---- K1: degree histograms, LDS byte-packed, 512 thr + int4 loads ----------
__global__ __launch_bounds__(512) void k_hist(const int* __restrict__ il,
                                              uint_t* __restrict__ packed) {
    __shared__ uint_t h[12500];
    int t = threadIdx.x, b = blockIdx.x;
    int hist  = b >> 7;          // 0 -> node (Dv), 1 -> edge (De)
    int range = (b >> 6) & 1;    // bins [range*50000, +50000)
    int slice = b & 63;          // contiguous 50K-pin slice

    for (int w = t; w < 12500; w += 512) h[w] = 0u;
    __syncthreads();

    const int4* idx4 = (const int4*)(il + (size_t)hist * NNZ_C + (size_t)slice * 50000);
    uint_t base = (uint_t)range * 50000u;
    for (int i = t; i < 12500; i += 512) {
        int4 v = idx4[i];
        uint_t u;
        u = (uint_t)v.x - base; if (u < 50000u) atomicAdd(&h[u >> 2], 1u << ((u & 3u) * 8u));
        u = (uint_t)v.y - base; if (u < 50000u) atomicAdd(&h[u >> 2], 1u << ((u & 3u) * 8u));
        u = (uint_t)v.z - base; if (u < 50000u) atomicAdd(&h[u >> 2], 1u << ((u & 3u) * 8u));
        u = (uint_t)v.w - base; if (u < 50000u) atomicAdd(&h[u >> 2], 1u << ((u & 3u) * 8u));
    }
    __syncthreads();

    uint_t* gp = packed + hist * 25000 + range * 12500;
    for (int w = t; w < 12500; w += 512) {
        uint_t v = h[w];
        if (v) atomicAdd(&gp[w], v);
    }
}

// ---- K2: unpack byte counters -> float Dv, De ------------------------------
__global__ __launch_bounds__(256) void k_unpack(const uint_t* __restrict__ packed,
                                                float* __restrict__ Dv,
                                                float* __restrict__ De) {
    int w = blockIdx.x * 256 + threadIdx.x;
    if (w < 50000) {
        uint_t v = packed[w];
        float4 f = make_float4((float)(v & 255u), (float)((v >> 8) & 255u),
                               (float)((v >> 16) & 255u), (float)(v >> 24));
        float* dst = (w < 25000) ? (Dv + (size_t)w * 4) : (De + (size_t)(w - 25000) * 4);
        *(float4*)dst = f;
    }
}

// ---- K3: nZ = Dv^-1/2 Z, f_Dv_f partials, separation stats -----------------
__global__ __launch_bounds__(256) void k_norm(const float* __restrict__ Z,
                                              const float* __restrict__ Dv,
                                              float* __restrict__ nZ,
                                              float* __restrict__ acc) {
    __shared__ float sacc[KD + 4];
    int t = threadIdx.x;
    if (t < KD + 4) sacc[t] = 0.f;
    __syncthreads();

    int n = blockIdx.x * 256 + t;
    if (n < NN_C) {
        float dv = fmaxf(Dv[n], EPSF);
        float inv = rsqrtf(dv);
        const float4* z4 = (const float4*)(Z + (size_t)n * KD);
        float4*       o4 = (float4*)(nZ + (size_t)n * KD);
        float zr[KD];
        #pragma unroll
        for (int i = 0; i < 4; ++i) {
            float4 z = z4[i];
            o4[i] = make_float4(z.x * inv, z.y * inv, z.z * inv, z.w * inv);
            zr[4*i+0] = z.x; zr[4*i+1] = z.y; zr[4*i+2] = z.z; zr[4*i+3] = z.w;
        }
        #pragma unroll
        for (int k = 0; k < KD; ++k) atomicAdd(&sacc[k], zr[k] * zr[k] * dv);
        float f = zr[0];
        if (f > 0.f)      { atomicAdd(&sacc[KD+0], f); atomicAdd(&sacc[KD+2], 1.f); }
        else if (f < 0.f) { atomicAdd(&sacc[KD+1], f); atomicAdd(&sacc[KD+3], 1.f); }
    }
    __syncthreads();
    if (t < KD)          atomicAdd(&acc[16 + t], sacc[t]);
    else if (t < KD + 4) atomicAdd(&acc[32 + (t - KD)], sacc[t]);
}

// ---- K4a: bucket pins by edge/BEDG into packed u32 records ------------------
__global__ __launch_bounds__(256) void k_bucket(const int* __restrict__ il,
                                                uint_t* __restrict__ cur,
                                                uint_t* __restrict__ recs) {
    __shared__ uint_t cnt[NBKT], bas[NBKT];
    int t = threadIdx.x;
    for (int i = t; i < NBKT; i += 256) cnt[i] = 0u;
    __syncthreads();

    int base = blockIdx.x * 4096;
    uint_t myrec[16], mybl[16];
    #pragma unroll
    for (int i = 0; i < 16; ++i) {
        int p = base + i * 256 + t;
        myrec[i] = 0xFFFFFFFFu;
        if (p < NNZ_C) {
            uint_t n = (uint_t)il[p];
            uint_t e = (uint_t)il[NNZ_C + p];
            uint_t bkt = e / BEDG;
            uint_t el  = e - bkt * BEDG;
            uint_t slot = atomicAdd(&cnt[bkt], 1u);
            myrec[i] = (n << 8) | el;            // el < 250 fits 8 bits
            mybl[i]  = (bkt << 16) | slot;
        }
    }
    __syncthreads();
    for (int i = t; i < NBKT; i += 256) bas[i] = atomicAdd(&cur[i], cnt[i]);
    __syncthreads();
    #pragma unroll
    for (int i = 0; i < 16; ++i) {
        if (myrec[i] != 0xFFFFFFFFu) {
            uint_t bkt = mybl[i] >> 16, slot = mybl[i] & 0xFFFFu;
            uint_t pos = bas[bkt] + slot;
            if (pos < RCAP) recs[(size_t)bkt * RCAP + pos] = myrec[i];
        }
    }
}

// ---- K4b: per-bucket LDS accumulation, 16 lanes per record ------------------
// block = bucket*SLICES + s; 250-edge S-subtile (16 KB) in LDS.
__global__ __launch_bounds__(512) void k_scan(const uint_t* __restrict__ recs,
                                              const uint_t* __restrict__ cur,
                                              const float* __restrict__ nZ,
                                              float* __restrict__ part) {
    __shared__ float Ss[BEDG * KD];            // 4000 floats, 16 KB
    int t = threadIdx.x;
    int bkt = blockIdx.x / SLICES, s = blockIdx.x % SLICES;

    for (int i = t; i < BEDG * KD / 4; i += 512)
        ((float4*)Ss)[i] = make_float4(0.f, 0.f, 0.f, 0.f);
    __syncthreads();

    uint_t c = cur[bkt];
    if (c > RCAP) c = RCAP;
    uint_t lo = (c * (uint_t)s) / SLICES, hi = (c * (uint_t)(s + 1)) / SLICES;
    const uint_t* r = recs + (size_t)bkt * RCAP;
    int k = t & 15;
    #pragma unroll 4
    for (uint_t i = lo + (uint_t)(t >> 4); i < hi; i += 32) {
        uint_t rc = r[i];                      // same addr across 16 lanes -> broadcast
        uint_t n = rc >> 8, el = rc & 255u;
        float v = nZ[(size_t)n * KD + k];      // coalesced 64B per record
        atomicAdd(&Ss[el * KD + k], v);        // one LDS atomic per lane
    }
    __syncthreads();

    float* gp = part + (size_t)blockIdx.x * (BEDG * KD);
    for (int i = t; i < BEDG * KD / 4; i += 512)
        ((float4*)gp)[i] = ((float4*)Ss)[i];
}

// ---- K4c: theta[k] = sum_e (sum_s part)^2 / De[e] ---------------------------
__global__ __launch_bounds__(256) void k_rtheta(const float* __restrict__ part,
                                                const float* __restrict__ De,
                                                float* __restrict__ acc) {
    __shared__ float sacc[KD];
    int t = threadIdx.x;
    if (t < KD) sacc[t] = 0.f;
    __syncthreads();

    uint_t gid = blockIdx.x * 256u + t;
    if (gid < (uint_t)NE_C * KD) {
        uint_t e = gid >> 4, k = gid & 15u;
        uint_t b = e / BEDG, el = e - b * BEDG;
        const float* p0 = part + (size_t)b * SLICES * (BEDG * KD) + el * KD + k;
        float sv = p0[0] + p0[BEDG * KD];
        float rinv = 1.f / fmaxf(De[e], EPSF);
        atomicAdd(&sacc[k], sv * sv * rinv);
    }
    __syncthreads();
    if (t < KD) atomicAdd(&acc[t], sacc[t]);
}

// ---- K5: finalize ------------------------------------------------------------
__global__ void k_final(const float* __restrict__ acc, float* __restrict__ out) {
    if (blockIdx.x == 0 && threadIdx.x == 0) {
        float rsum = 0.f;
        #pragma unroll
        for (int k = 0; k < KD; ++k) {
            float theta = acc[k];
            float fd    = fmaxf(acc[16 + k], EPSF);
            float rq    = 1.f - theta / fd;
            if (!isfinite(rq)) rq = 0.f;
            rsum += rq;
        }
        float rl = rsum / (float)KD;
        float pS = acc[32], nS = acc[33], pC = acc[34], nC = acc[35];
        float pm = pS / fmaxf(pC, 1.f);
        float nm = nS / fmaxf(nC, 1.f);
        float sep = fabsf(pm - nm);
        float pen = (pC == 0.f || nC == 0.f) ? 1.f : 1.f / (sep + EPSF);
        out[0] = rl + LSEP * pen;
    }
}

extern "C" void kernel_launch(void* const* d_in, const int* in_sizes, int n_in,
                              void* d_out, int out_size, void* d_ws, size_t ws_size,
                              hipStream_t stream) {
    const float* Z  = (const float*)d_in[0];
    const int*   il = (const int*)d_in[1];   // (2, NNZ) int32
    float*  ws     = (float*)d_ws;
    uint_t* packed = (uint_t*)d_ws;
    uint_t* cur    = (uint_t*)d_ws + W_CUR;
    float*  acc    = ws + W_ACC;
    float*  Dv     = ws + W_DV;
    float*  De     = ws + W_DE;
    float*  nZ     = ws + W_NZ;
    uint_t* recs   = (uint_t*)d_ws + W_REC;
    float*  part   = ws + W_PART;
    float*  out    = (float*)d_out;

    // zero packed counters + cursors + acc (rest fully overwritten)
    hipMemsetAsync(ws, 0, (size_t)W_ZERO * sizeof(float), stream);

    k_hist  <<<256, 512, 0, stream>>>(il, packed);
    k_unpack<<<(50000 + 255) / 256, 256, 0, stream>>>(packed, Dv, De);
    k_norm  <<<(NN_C + 255) / 256, 256, 0, stream>>>(Z, Dv, nZ, acc);
    k_bucket<<<(NNZ_C + 4095) / 4096, 256, 0, stream>>>(il, cur, recs);
    k_scan  <<<NBKT * SLICES, 512, 0, stream>>>(recs, cur, nZ, part);
    k_rtheta<<<(NE_C * KD + 255) / 256, 256, 0, stream>>>(part, De, acc);
    k_final <<<1, 64, 0, stream>>>(acc, out);
}

// Round 6
// 426.630 us; speedup vs baseline: 1.2282x; 1.2282x over previous
//
#include <hip/hip_runtime.h>
#include <math.h>

#define NNZ_C 3200000
#define NN_C  100000
#define NE_C  100000
#define KD    16
#define EPSF  1e-6f
#define LSEP  0.1f

#define NBKT   800         // buckets
#define BEDG   125         // edges per bucket (NBKT*BEDG = NE_C)
#define RCAP   4480        // record capacity per bucket (mean 4000, +7.6 sigma)
#define SLICES 4           // scan blocks per bucket

typedef unsigned int uint_t;

// ---------- workspace layout (word offsets), total ~28.1 MB ----------
//   [0, 50000)            packed degree counters (u32, 4x8-bit bins)   (zeroed)
//   [50000, 51024)        bucket cursors (NBKT used)                   (zeroed)
//   [51024, 51088)        acc: theta[0..15], fdvf[16..31], sep[32..35] (zeroed)
//   [51088, +1600000)     S (edge-major accumulators)                  (zeroed)
//   [W_DV, +100000)       Dv (fully written by k_unpack)
//   [W_DE, +100000)       De (fully written by k_unpack)
//   [W_NZ, +1600000)      nZ (fully written by k_norm)
//   [W_REC, +NBKT*RCAP)   bucket records u32
#define W_PK    0
#define W_CUR   50000
#define W_ACC   51024
#define W_S     51088
#define W_DV    (W_S + NE_C * KD)
#define W_DE    (W_DV + NN_C)
#define W_NZ    (W_DE + NN_C)
#define W_REC   (W_NZ + NN_C * KD)
#define W_END   (W_REC + NBKT * RCAP)
#define W_ZERO  W_DV        // zero pk + cur + acc + S

// ---- K1: degree histograms, LDS byte-packed, 512 thr + int4 loads ----------
__global__ __launch_bounds__(512) void k_hist(const int* __restrict__ il,
                                              uint_t* __restrict__ packed) {
    __shared__ uint_t h[12500];
    int t = threadIdx.x, b = blockIdx.x;
    int hist  = b >> 7;          // 0 -> node (Dv), 1 -> edge (De)
    int range = (b >> 6) & 1;    // bins [range*50000, +50000)
    int slice = b & 63;          // contiguous 50K-pin slice

    for (int w = t; w < 12500; w += 512) h[w] = 0u;
    __syncthreads();

    const int4* idx4 = (const int4*)(il + (size_t)hist * NNZ_C + (size_t)slice * 50000);
    uint_t base = (uint_t)range * 50000u;
    for (int i = t; i < 12500; i += 512) {
        int4 v = idx4[i];
        uint_t u;
        u = (uint_t)v.x - base; if (u < 50000u) atomicAdd(&h[u >> 2], 1u << ((u & 3u) * 8u));
        u = (uint_t)v.y - base; if (u < 50000u) atomicAdd(&h[u >> 2], 1u << ((u & 3u) * 8u));
        u = (uint_t)v.z - base; if (u < 50000u) atomicAdd(&h[u >> 2], 1u << ((u & 3u) * 8u));
        u = (uint_t)v.w - base; if (u < 50000u) atomicAdd(&h[u >> 2], 1u << ((u & 3u) * 8u));
    }
    __syncthreads();

    uint_t* gp = packed + hist * 25000 + range * 12500;
    for (int w = t; w < 12500; w += 512) {
        uint_t v = h[w];
        if (v) atomicAdd(&gp[w], v);
    }
}

// ---- K2: unpack byte counters -> float Dv, De ------------------------------
__global__ __launch_bounds__(256) void k_unpack(const uint_t* __restrict__ packed,
                                                float* __restrict__ Dv,
                                                float* __restrict__ De) {
    int w = blockIdx.x * 256 + threadIdx.x;
    if (w < 50000) {
        uint_t v = packed[w];
        float4 f = make_float4((float)(v & 255u), (float)((v >> 8) & 255u),
                               (float)((v >> 16) & 255u), (float)(v >> 24));
        float* dst = (w < 25000) ? (Dv + (size_t)w * 4) : (De + (size_t)(w - 25000) * 4);
        *(float4*)dst = f;
    }
}

// ---- K3: nZ = Dv^-1/2 Z, f_Dv_f partials, separation stats -----------------
__global__ __launch_bounds__(256) void k_norm(const float* __restrict__ Z,
                                              const float* __restrict__ Dv,
                                              float* __restrict__ nZ,
                                              float* __restrict__ acc) {
    __shared__ float sacc[KD + 4];
    int t = threadIdx.x;
    if (t < KD + 4) sacc[t] = 0.f;
    __syncthreads();

    int n = blockIdx.x * 256 + t;
    if (n < NN_C) {
        float dv = fmaxf(Dv[n], EPSF);
        float inv = rsqrtf(dv);
        const float4* z4 = (const float4*)(Z + (size_t)n * KD);
        float4*       o4 = (float4*)(nZ + (size_t)n * KD);
        float zr[KD];
        #pragma unroll
        for (int i = 0; i < 4; ++i) {
            float4 z = z4[i];
            o4[i] = make_float4(z.x * inv, z.y * inv, z.z * inv, z.w * inv);
            zr[4*i+0] = z.x; zr[4*i+1] = z.y; zr[4*i+2] = z.z; zr[4*i+3] = z.w;
        }
        #pragma unroll
        for (int k = 0; k < KD; ++k) atomicAdd(&sacc[k], zr[k] * zr[k] * dv);
        float f = zr[0];
        if (f > 0.f)      { atomicAdd(&sacc[KD+0], f); atomicAdd(&sacc[KD+2], 1.f); }
        else if (f < 0.f) { atomicAdd(&sacc[KD+1], f); atomicAdd(&sacc[KD+3], 1.f); }
    }
    __syncthreads();
    if (t < KD)          atomicAdd(&acc[16 + t], sacc[t]);
    else if (t < KD + 4) atomicAdd(&acc[32 + (t - KD)], sacc[t]);
}

// ---- K4a: bucket pins by edge/BEDG into packed u32 records ------------------
__global__ __launch_bounds__(256) void k_bucket(const int* __restrict__ il,
                                                uint_t* __restrict__ cur,
                                                uint_t* __restrict__ recs) {
    __shared__ uint_t cnt[NBKT], bas[NBKT];
    int t = threadIdx.x;
    for (int i = t; i < NBKT; i += 256) cnt[i] = 0u;
    __syncthreads();

    int base = blockIdx.x * 4096;
    uint_t myrec[16], mybl[16];
    #pragma unroll
    for (int i = 0; i < 16; ++i) {
        int p = base + i * 256 + t;
        myrec[i] = 0xFFFFFFFFu;
        if (p < NNZ_C) {
            uint_t n = (uint_t)il[p];
            uint_t e = (uint_t)il[NNZ_C + p];
            uint_t bkt = e / BEDG;
            uint_t el  = e - bkt * BEDG;
            uint_t slot = atomicAdd(&cnt[bkt], 1u);
            myrec[i] = (n << 7) | el;            // el < 125 fits 7 bits
            mybl[i]  = (bkt << 16) | slot;
        }
    }
    __syncthreads();
    for (int i = t; i < NBKT; i += 256) bas[i] = cnt[i] ? atomicAdd(&cur[i], cnt[i]) : 0u;
    __syncthreads();
    #pragma unroll
    for (int i = 0; i < 16; ++i) {
        if (myrec[i] != 0xFFFFFFFFu) {
            uint_t bkt = mybl[i] >> 16, slot = mybl[i] & 0xFFFFu;
            uint_t pos = bas[bkt] + slot;
            if (pos < RCAP) recs[(size_t)bkt * RCAP + pos] = myrec[i];
        }
    }
}

// ---- K4b: per-bucket LDS accumulation, 16 lanes/record, 4-deep batches ------
// block = bucket*SLICES + s; 125-edge S-subtile (8 KB) in LDS; flush = coalesced
// global atomics into edge-major S.
__global__ __launch_bounds__(512) void k_scan(const uint_t* __restrict__ recs,
                                              const uint_t* __restrict__ cur,
                                              const float* __restrict__ nZ,
                                              float* __restrict__ S) {
    __shared__ float Ss[BEDG * KD];            // 2000 floats, 8 KB
    int t = threadIdx.x;
    int bkt = blockIdx.x >> 2, s = blockIdx.x & 3;

    for (int i = t; i < BEDG * KD / 4; i += 512)
        ((float4*)Ss)[i] = make_float4(0.f, 0.f, 0.f, 0.f);
    __syncthreads();

    uint_t c = cur[bkt];
    if (c > RCAP) c = RCAP;
    uint_t lo = (c * (uint_t)s) >> 2, hi = (c * (uint_t)(s + 1)) >> 2;
    const uint_t* r = recs + (size_t)bkt * RCAP;
    int k = t & 15;
    uint_t i = lo + (uint_t)(t >> 4);          // 32 groups per block

    // 4-deep batched main loop: 4 independent record loads -> 4 gathers -> 4 LDS atomics
    for (; i + 96 < hi; i += 128) {
        uint_t rc0 = r[i], rc1 = r[i + 32], rc2 = r[i + 64], rc3 = r[i + 96];
        float v0 = nZ[(size_t)(rc0 >> 7) * KD + k];
        float v1 = nZ[(size_t)(rc1 >> 7) * KD + k];
        float v2 = nZ[(size_t)(rc2 >> 7) * KD + k];
        float v3 = nZ[(size_t)(rc3 >> 7) * KD + k];
        atomicAdd(&Ss[(rc0 & 127u) * KD + k], v0);
        atomicAdd(&Ss[(rc1 & 127u) * KD + k], v1);
        atomicAdd(&Ss[(rc2 & 127u) * KD + k], v2);
        atomicAdd(&Ss[(rc3 & 127u) * KD + k], v3);
    }
    for (; i < hi; i += 32) {
        uint_t rc = r[i];
        float v = nZ[(size_t)(rc >> 7) * KD + k];
        atomicAdd(&Ss[(rc & 127u) * KD + k], v);
    }
    __syncthreads();

    // flush tile -> global S (contiguous coalesced dword atomics)
    float* gS = S + (size_t)bkt * (BEDG * KD);
    for (int j = t; j < BEDG * KD; j += 512)
        atomicAdd(&gS[j], Ss[j]);
}

// ---- K4c: theta[k] = sum_e S[e,k]^2 / De[e] ---------------------------------
__global__ __launch_bounds__(256) void k_theta(const float* __restrict__ S,
                                               const float* __restrict__ De,
                                               float* __restrict__ acc) {
    __shared__ float sacc[KD];
    int t = threadIdx.x;
    if (t < KD) sacc[t] = 0.f;
    __syncthreads();
    int e = blockIdx.x * 256 + t;
    if (e < NE_C) {
        float rinv = 1.f / fmaxf(De[e], EPSF);
        const float4* s4 = (const float4*)(S + (size_t)e * KD);
        #pragma unroll
        for (int i = 0; i < 4; ++i) {
            float4 s = s4[i];
            atomicAdd(&sacc[4*i+0], s.x * s.x * rinv);
            atomicAdd(&sacc[4*i+1], s.y * s.y * rinv);
            atomicAdd(&sacc[4*i+2], s.z * s.z * rinv);
            atomicAdd(&sacc[4*i+3], s.w * s.w * rinv);
        }
    }
    __syncthreads();
    if (t < KD) atomicAdd(&acc[t], sacc[t]);
}

// ---- K5: finalize ------------------------------------------------------------
__global__ void k_final(const float* __restrict__ acc, float* __restrict__ out) {
    if (blockIdx.x == 0 && threadIdx.x == 0) {
        float rsum = 0.f;
        #pragma unroll
        for (int k = 0; k < KD; ++k) {
            float theta = acc[k];
            float fd    = fmaxf(acc[16 + k], EPSF);
            float rq    = 1.f - theta / fd;
            if (!isfinite(rq)) rq = 0.f;
            rsum += rq;
        }
        float rl = rsum / (float)KD;
        float pS = acc[32], nS = acc[33], pC = acc[34], nC = acc[35];
        float pm = pS / fmaxf(pC, 1.f);
        float nm = nS / fmaxf(nC, 1.f);
        float sep = fabsf(pm - nm);
        float pen = (pC == 0.f || nC == 0.f) ? 1.f : 1.f / (sep + EPSF);
        out[0] = rl + LSEP * pen;
    }
}

extern "C" void kernel_launch(void* const* d_in, const int* in_sizes, int n_in,
                              void* d_out, int out_size, void* d_ws, size_t ws_size,
                              hipStream_t stream) {
    const float* Z  = (const float*)d_in[0];
    const int*   il = (const int*)d_in[1];   // (2, NNZ) int32
    float*  ws     = (float*)d_ws;
    uint_t* packed = (uint_t*)d_ws;
    uint_t* cur    = (uint_t*)d_ws + W_CUR;
    float*  acc    = ws + W_ACC;
    float*  S      = ws + W_S;
    float*  Dv     = ws + W_DV;
    float*  De     = ws + W_DE;
    float*  nZ     = ws + W_NZ;
    uint_t* recs   = (uint_t*)d_ws + W_REC;
    float*  out    = (float*)d_out;

    // zero packed counters + cursors + acc + S (rest fully overwritten)
    hipMemsetAsync(ws, 0, (size_t)W_ZERO * sizeof(float), stream);

    k_hist  <<<256, 512, 0, stream>>>(il, packed);
    k_unpack<<<(50000 + 255) / 256, 256, 0, stream>>>(packed, Dv, De);
    k_norm  <<<(NN_C + 255) / 256, 256, 0, stream>>>(Z, Dv, nZ, acc);
    k_bucket<<<(NNZ_C + 4095) / 4096, 256, 0, stream>>>(il, cur, recs);
    k_scan  <<<NBKT * SLICES, 512, 0, stream>>>(recs, cur, nZ, S);
    k_theta <<<(NE_C + 255) / 256, 256, 0, stream>>>(S, De, acc);
    k_final <<<1, 64, 0, stream>>>(acc, out);
}

// Round 7
// 400.620 us; speedup vs baseline: 1.3079x; 1.0649x over previous
//
#include <hip/hip_runtime.h>
#include <math.h>
#include <stdint.h>

#define NNZ_C 3200000
#define NN_C  100000
#define NE_C  100000
#define KD    16
#define EPSF  1e-6f
#define LSEP  0.1f

#define NBKT   800         // buckets
#define BEDG   125         // edges per bucket (NBKT*BEDG = NE_C)
#define RCAP   4480        // record capacity per bucket (mean 4000, +7.6 sigma)
#define SLICES 4           // scan blocks per bucket

typedef unsigned int uint_t;

// ---------- workspace layout (word offsets), total ~28.0 MB ----------
//   [W_PK, +25000)      node degree packed counters (u32, 4x8-bit)  (zeroed)
//   [W_CUR, +1024)      bucket cursors                              (zeroed)
//   [W_ACC, +64)        acc: theta[0..15], fdvf[16..31], sep[32..35](zeroed)
//   [W_CNTE, +100000)   De integer counts (u32)                     (zeroed)
//   [W_S, +1600000)     S (edge-major accumulators)                 (zeroed)
//   [W_DV, +100000)     Dv float (fully written by k_unpack)
//   [W_NZ, +1600000)    nZ (fully written by k_norm)
//   [W_REC, +NBKT*RCAP) bucket records u32
#define W_PK    0
#define W_CUR   25000
#define W_ACC   26024
#define W_CNTE  26088
#define W_S     126088
#define W_DV    (W_S + NE_C * KD)
#define W_NZ    (W_DV + NN_C)
#define W_REC   (W_NZ + NN_C * KD)
#define W_END   (W_REC + NBKT * RCAP)
#define W_ZERO  W_DV        // zero everything below W_DV

// Native LDS float atomic add (ds_add_f32). HIP's atomicAdd on __shared__
// float compiles to a CAS loop (no -munsafe-fp-atomics), which serializes the
// surrounding loads (round-6: VGPR=12, VALUBusy 3.4%). Low 32 bits of a flat
// LDS pointer are the LDS byte offset on gfx9-lineage apertures.
__device__ __forceinline__ void lds_fadd(float* p, float v) {
    asm volatile("ds_add_f32 %0, %1"
                 :
                 : "v"((uint32_t)(uintptr_t)p), "v"(v)
                 : "memory");
}

// ---- K1: node degree histogram, LDS byte-packed ----------------------------
__global__ __launch_bounds__(512) void k_hist(const int* __restrict__ il,
                                              uint_t* __restrict__ packed) {
    __shared__ uint_t h[12500];
    int t = threadIdx.x, b = blockIdx.x;
    int range = b >> 6;          // bins [range*50000, +50000)
    int slice = b & 63;          // contiguous 50K-pin slice

    for (int w = t; w < 12500; w += 512) h[w] = 0u;
    __syncthreads();

    const int4* idx4 = (const int4*)(il + (size_t)slice * 50000);
    uint_t base = (uint_t)range * 50000u;
    for (int i = t; i < 12500; i += 512) {
        int4 v = idx4[i];
        uint_t u;
        u = (uint_t)v.x - base; if (u < 50000u) atomicAdd(&h[u >> 2], 1u << ((u & 3u) * 8u));
        u = (uint_t)v.y - base; if (u < 50000u) atomicAdd(&h[u >> 2], 1u << ((u & 3u) * 8u));
        u = (uint_t)v.z - base; if (u < 50000u) atomicAdd(&h[u >> 2], 1u << ((u & 3u) * 8u));
        u = (uint_t)v.w - base; if (u < 50000u) atomicAdd(&h[u >> 2], 1u << ((u & 3u) * 8u));
    }
    __syncthreads();

    uint_t* gp = packed + range * 12500;
    for (int w = t; w < 12500; w += 512) {
        uint_t v = h[w];
        if (v) atomicAdd(&gp[w], v);
    }
}

// ---- K2: unpack byte counters -> float Dv ----------------------------------
__global__ __launch_bounds__(256) void k_unpack(const uint_t* __restrict__ packed,
                                                float* __restrict__ Dv) {
    int w = blockIdx.x * 256 + threadIdx.x;
    if (w < 25000) {
        uint_t v = packed[w];
        float4 f = make_float4((float)(v & 255u), (float)((v >> 8) & 255u),
                               (float)((v >> 16) & 255u), (float)(v >> 24));
        *(float4*)(Dv + (size_t)w * 4) = f;
    }
}

// ---- K3: nZ = Dv^-1/2 Z, f_Dv_f partials, separation stats -----------------
__global__ __launch_bounds__(256) void k_norm(const float* __restrict__ Z,
                                              const float* __restrict__ Dv,
                                              float* __restrict__ nZ,
                                              float* __restrict__ acc) {
    __shared__ float sacc[KD + 4];
    int t = threadIdx.x;
    if (t < KD + 4) sacc[t] = 0.f;
    __syncthreads();

    int n = blockIdx.x * 256 + t;
    if (n < NN_C) {
        float dv = fmaxf(Dv[n], EPSF);
        float inv = rsqrtf(dv);
        const float4* z4 = (const float4*)(Z + (size_t)n * KD);
        float4*       o4 = (float4*)(nZ + (size_t)n * KD);
        float zr[KD];
        #pragma unroll
        for (int i = 0; i < 4; ++i) {
            float4 z = z4[i];
            o4[i] = make_float4(z.x * inv, z.y * inv, z.z * inv, z.w * inv);
            zr[4*i+0] = z.x; zr[4*i+1] = z.y; zr[4*i+2] = z.z; zr[4*i+3] = z.w;
        }
        #pragma unroll
        for (int k = 0; k < KD; ++k) lds_fadd(&sacc[k], zr[k] * zr[k] * dv);
        float f = zr[0];
        if (f > 0.f)      { lds_fadd(&sacc[KD+0], f); lds_fadd(&sacc[KD+2], 1.f); }
        else if (f < 0.f) { lds_fadd(&sacc[KD+1], f); lds_fadd(&sacc[KD+3], 1.f); }
    }
    __syncthreads();
    if (t < KD)          atomicAdd(&acc[16 + t], sacc[t]);
    else if (t < KD + 4) atomicAdd(&acc[32 + (t - KD)], sacc[t]);
}

// ---- K4a: bucket pins by edge/BEDG into packed u32 records ------------------
__global__ __launch_bounds__(256) void k_bucket(const int* __restrict__ il,
                                                uint_t* __restrict__ cur,
                                                uint_t* __restrict__ recs) {
    __shared__ uint_t cnt[NBKT], bas[NBKT];
    int t = threadIdx.x;
    for (int i = t; i < NBKT; i += 256) cnt[i] = 0u;
    __syncthreads();

    int base = blockIdx.x * 4096;
    uint_t myrec[16], mybl[16];
    #pragma unroll
    for (int i = 0; i < 16; ++i) {
        int p = base + i * 256 + t;
        myrec[i] = 0xFFFFFFFFu;
        if (p < NNZ_C) {
            uint_t n = (uint_t)il[p];
            uint_t e = (uint_t)il[NNZ_C + p];
            uint_t bkt = e / BEDG;
            uint_t el  = e - bkt * BEDG;
            uint_t slot = atomicAdd(&cnt[bkt], 1u);
            myrec[i] = (n << 7) | el;            // el < 125 fits 7 bits
            mybl[i]  = (bkt << 16) | slot;
        }
    }
    __syncthreads();
    for (int i = t; i < NBKT; i += 256) bas[i] = cnt[i] ? atomicAdd(&cur[i], cnt[i]) : 0u;
    __syncthreads();
    #pragma unroll
    for (int i = 0; i < 16; ++i) {
        if (myrec[i] != 0xFFFFFFFFu) {
            uint_t bkt = mybl[i] >> 16, slot = mybl[i] & 0xFFFFu;
            uint_t pos = bas[bkt] + slot;
            if (pos < RCAP) recs[(size_t)bkt * RCAP + pos] = myrec[i];
        }
    }
}

// ---- K4b: per-bucket LDS accumulation, native ds_add_f32, De counting -------
__global__ __launch_bounds__(512) void k_scan(const uint_t* __restrict__ recs,
                                              const uint_t* __restrict__ cur,
                                              const float* __restrict__ nZ,
                                              float* __restrict__ S,
                                              uint_t* __restrict__ cntE) {
    __shared__ __align__(16) float Ss[BEDG * KD];   // 8 KB
    __shared__ uint_t Ce[BEDG];
    int t = threadIdx.x;
    int bkt = blockIdx.x >> 2, s = blockIdx.x & 3;

    for (int i = t; i < BEDG * KD / 4; i += 512)
        ((float4*)Ss)[i] = make_float4(0.f, 0.f, 0.f, 0.f);
    if (t < BEDG) Ce[t] = 0u;
    __syncthreads();

    uint_t c = cur[bkt];
    if (c > RCAP) c = RCAP;
    uint_t lo = (c * (uint_t)s) >> 2, hi = (c * (uint_t)(s + 1)) >> 2;
    const uint_t* r = recs + (size_t)bkt * RCAP;
    int k = t & 15;
    bool lane0 = (k == 0);
    uint_t i = lo + (uint_t)(t >> 4);          // 32 groups per block

    for (; i + 96 < hi; i += 128) {
        uint_t rc0 = r[i], rc1 = r[i + 32], rc2 = r[i + 64], rc3 = r[i + 96];
        float v0 = nZ[(size_t)(rc0 >> 7) * KD + k];
        float v1 = nZ[(size_t)(rc1 >> 7) * KD + k];
        float v2 = nZ[(size_t)(rc2 >> 7) * KD + k];
        float v3 = nZ[(size_t)(rc3 >> 7) * KD + k];
        if (lane0) {
            atomicAdd(&Ce[rc0 & 127u], 1u);     // native ds_add_u32
            atomicAdd(&Ce[rc1 & 127u], 1u);
            atomicAdd(&Ce[rc2 & 127u], 1u);
            atomicAdd(&Ce[rc3 & 127u], 1u);
        }
        lds_fadd(&Ss[(rc0 & 127u) * KD + k], v0);
        lds_fadd(&Ss[(rc1 & 127u) * KD + k], v1);
        lds_fadd(&Ss[(rc2 & 127u) * KD + k], v2);
        lds_fadd(&Ss[(rc3 & 127u) * KD + k], v3);
    }
    for (; i < hi; i += 32) {
        uint_t rc = r[i];
        float v = nZ[(size_t)(rc >> 7) * KD + k];
        if (lane0) atomicAdd(&Ce[rc & 127u], 1u);
        lds_fadd(&Ss[(rc & 127u) * KD + k], v);
    }
    __syncthreads();

    // flush tile -> global (contiguous coalesced atomics)
    float* gS = S + (size_t)bkt * (BEDG * KD);
    for (int j = t; j < BEDG * KD; j += 512)
        atomicAdd(&gS[j], Ss[j]);
    if (t < BEDG) {
        uint_t cv = Ce[t];
        if (cv) atomicAdd(&cntE[bkt * BEDG + t], cv);
    }
}

// ---- K4c: theta[k] = sum_e S[e,k]^2 / De[e] ---------------------------------
__global__ __launch_bounds__(256) void k_theta(const float* __restrict__ S,
                                               const uint_t* __restrict__ cntE,
                                               float* __restrict__ acc) {
    __shared__ float sacc[KD];
    int t = threadIdx.x;
    if (t < KD) sacc[t] = 0.f;
    __syncthreads();
    int e = blockIdx.x * 256 + t;
    if (e < NE_C) {
        float rinv = 1.f / fmaxf((float)cntE[e], EPSF);
        const float4* s4 = (const float4*)(S + (size_t)e * KD);
        #pragma unroll
        for (int i = 0; i < 4; ++i) {
            float4 s = s4[i];
            lds_fadd(&sacc[4*i+0], s.x * s.x * rinv);
            lds_fadd(&sacc[4*i+1], s.y * s.y * rinv);
            lds_fadd(&sacc[4*i+2], s.z * s.z * rinv);
            lds_fadd(&sacc[4*i+3], s.w * s.w * rinv);
        }
    }
    __syncthreads();
    if (t < KD) atomicAdd(&acc[t], sacc[t]);
}

// ---- K5: finalize ------------------------------------------------------------
__global__ void k_final(const float* __restrict__ acc, float* __restrict__ out) {
    if (blockIdx.x == 0 && threadIdx.x == 0) {
        float rsum = 0.f;
        #pragma unroll
        for (int k = 0; k < KD; ++k) {
            float theta = acc[k];
            float fd    = fmaxf(acc[16 + k], EPSF);
            float rq    = 1.f - theta / fd;
            if (!isfinite(rq)) rq = 0.f;
            rsum += rq;
        }
        float rl = rsum / (float)KD;
        float pS = acc[32], nS = acc[33], pC = acc[34], nC = acc[35];
        float pm = pS / fmaxf(pC, 1.f);
        float nm = nS / fmaxf(nC, 1.f);
        float sep = fabsf(pm - nm);
        float pen = (pC == 0.f || nC == 0.f) ? 1.f : 1.f / (sep + EPSF);
        out[0] = rl + LSEP * pen;
    }
}

extern "C" void kernel_launch(void* const* d_in, const int* in_sizes, int n_in,
                              void* d_out, int out_size, void* d_ws, size_t ws_size,
                              hipStream_t stream) {
    const float* Z  = (const float*)d_in[0];
    const int*   il = (const int*)d_in[1];   // (2, NNZ) int32
    float*  ws     = (float*)d_ws;
    uint_t* packed = (uint_t*)d_ws + W_PK;
    uint_t* cur    = (uint_t*)d_ws + W_CUR;
    float*  acc    = ws + W_ACC;
    uint_t* cntE   = (uint_t*)d_ws + W_CNTE;
    float*  S      = ws + W_S;
    float*  Dv     = ws + W_DV;
    float*  nZ     = ws + W_NZ;
    uint_t* recs   = (uint_t*)d_ws + W_REC;
    float*  out    = (float*)d_out;

    // zero packed + cursors + acc + cntE + S (rest fully overwritten)
    hipMemsetAsync(ws, 0, (size_t)W_ZERO * sizeof(float), stream);

    k_hist  <<<128, 512, 0, stream>>>(il, packed);
    k_unpack<<<(25000 + 255) / 256, 256, 0, stream>>>(packed, Dv);
    k_norm  <<<(NN_C + 255) / 256, 256, 0, stream>>>(Z, Dv, nZ, acc);
    k_bucket<<<(NNZ_C + 4095) / 4096, 256, 0, stream>>>(il, cur, recs);
    k_scan  <<<NBKT * SLICES, 512, 0, stream>>>(recs, cur, nZ, S, cntE);
    k_theta <<<(NE_C + 255) / 256, 256, 0, stream>>>(S, cntE, acc);
    k_final <<<1, 64, 0, stream>>>(acc, out);
}

// Round 8
// 395.786 us; speedup vs baseline: 1.3239x; 1.0122x over previous
//
#include <hip/hip_runtime.h>
#include <hip/hip_fp16.h>
#include <math.h>
#include <stdint.h>

#define NNZ_C 3200000
#define NN_C  100000
#define NE_C  100000
#define KD    16
#define EPSF  1e-6f
#define LSEP  0.1f

#define NBKT   800         // buckets
#define BEDG   125         // edges per bucket (NBKT*BEDG = NE_C)
#define RCAP   4480        // record capacity per bucket (mean 4000, +7.6 sigma)
#define SLICES 4           // scan blocks per bucket

typedef unsigned int uint_t;

// ---------- workspace layout (word offsets), total ~24.8 MB ----------
//   [W_PK, +25000)      node degree packed counters (u32, 4x8-bit)  (zeroed)
//   [W_CUR, +1024)      bucket cursors                              (zeroed)
//   [W_ACC, +64)        acc: theta[0..15], fdvf[16..31], sep[32..35](zeroed)
//   [W_CNTE, +100000)   De integer counts (u32)                     (zeroed)
//   [W_S, +1600000)     S (edge-major accumulators)                 (zeroed)
//   [W_DV, +100000)     Dv float (fully written by k_unpack)
//   [W_NZ, +800000)     nZ in fp16 (fully written by k_norm) — 3.2 MB,
//                       fits a 4 MB per-XCD L2 (fp32 was 6.4 MB -> 55% miss)
//   [W_REC, +NBKT*RCAP) bucket records u32
#define W_PK    0
#define W_CUR   25000
#define W_ACC   26024
#define W_CNTE  26088
#define W_S     126088
#define W_DV    (W_S + NE_C * KD)
#define W_NZ    (W_DV + NN_C)
#define W_REC   (W_NZ + NN_C * KD / 2)
#define W_END   (W_REC + NBKT * RCAP)
#define W_ZERO  W_DV        // zero everything below W_DV

// Native LDS float atomic add (ds_add_f32): HIP's atomicAdd on __shared__
// float is a CAS loop. Low 32 bits of a flat LDS pointer are the LDS byte
// offset (verified: round-7 passed with absmax 0.0).
__device__ __forceinline__ void lds_fadd(float* p, float v) {
    asm volatile("ds_add_f32 %0, %1"
                 :
                 : "v"((uint32_t)(uintptr_t)p), "v"(v)
                 : "memory");
}

// ---- K1: node degree histogram, LDS byte-packed ----------------------------
__global__ __launch_bounds__(512) void k_hist(const int* __restrict__ il,
                                              uint_t* __restrict__ packed) {
    __shared__ uint_t h[12500];
    int t = threadIdx.x, b = blockIdx.x;
    int range = b >> 6;          // bins [range*50000, +50000)
    int slice = b & 63;          // contiguous 50K-pin slice

    for (int w = t; w < 12500; w += 512) h[w] = 0u;
    __syncthreads();

    const int4* idx4 = (const int4*)(il + (size_t)slice * 50000);
    uint_t base = (uint_t)range * 50000u;
    for (int i = t; i < 12500; i += 512) {
        int4 v = idx4[i];
        uint_t u;
        u = (uint_t)v.x - base; if (u < 50000u) atomicAdd(&h[u >> 2], 1u << ((u & 3u) * 8u));
        u = (uint_t)v.y - base; if (u < 50000u) atomicAdd(&h[u >> 2], 1u << ((u & 3u) * 8u));
        u = (uint_t)v.z - base; if (u < 50000u) atomicAdd(&h[u >> 2], 1u << ((u & 3u) * 8u));
        u = (uint_t)v.w - base; if (u < 50000u) atomicAdd(&h[u >> 2], 1u << ((u & 3u) * 8u));
    }
    __syncthreads();

    uint_t* gp = packed + range * 12500;
    for (int w = t; w < 12500; w += 512) {
        uint_t v = h[w];
        if (v) atomicAdd(&gp[w], v);
    }
}

// ---- K2: unpack byte counters -> float Dv ----------------------------------
__global__ __launch_bounds__(256) void k_unpack(const uint_t* __restrict__ packed,
                                                float* __restrict__ Dv) {
    int w = blockIdx.x * 256 + threadIdx.x;
    if (w < 25000) {
        uint_t v = packed[w];
        float4 f = make_float4((float)(v & 255u), (float)((v >> 8) & 255u),
                               (float)((v >> 16) & 255u), (float)(v >> 24));
        *(float4*)(Dv + (size_t)w * 4) = f;
    }
}

// ---- K3: nZ(fp16) = Dv^-1/2 Z, f_Dv_f partials, separation stats -----------
__global__ __launch_bounds__(256) void k_norm(const float* __restrict__ Z,
                                              const float* __restrict__ Dv,
                                              __half* __restrict__ nZh,
                                              float* __restrict__ acc) {
    __shared__ float sacc[KD + 4];
    int t = threadIdx.x;
    if (t < KD + 4) sacc[t] = 0.f;
    __syncthreads();

    int n = blockIdx.x * 256 + t;
    if (n < NN_C) {
        float dv = fmaxf(Dv[n], EPSF);
        float inv = rsqrtf(dv);
        const float4* z4 = (const float4*)(Z + (size_t)n * KD);
        float zr[KD];
        #pragma unroll
        for (int i = 0; i < 4; ++i) {
            float4 z = z4[i];
            zr[4*i+0] = z.x; zr[4*i+1] = z.y; zr[4*i+2] = z.z; zr[4*i+3] = z.w;
        }
        uint4 u[2];
        __half2* hu = (__half2*)u;
        #pragma unroll
        for (int j = 0; j < 8; ++j)
            hu[j] = __floats2half2_rn(zr[2*j] * inv, zr[2*j+1] * inv);
        uint4* o = (uint4*)(nZh + (size_t)n * KD);
        o[0] = u[0];
        o[1] = u[1];
        #pragma unroll
        for (int k = 0; k < KD; ++k) lds_fadd(&sacc[k], zr[k] * zr[k] * dv);
        float f = zr[0];
        if (f > 0.f)      { lds_fadd(&sacc[KD+0], f); lds_fadd(&sacc[KD+2], 1.f); }
        else if (f < 0.f) { lds_fadd(&sacc[KD+1], f); lds_fadd(&sacc[KD+3], 1.f); }
    }
    __syncthreads();
    if (t < KD)          atomicAdd(&acc[16 + t], sacc[t]);
    else if (t < KD + 4) atomicAdd(&acc[32 + (t - KD)], sacc[t]);
}

// ---- K4a: bucket pins by edge/BEDG into packed u32 records ------------------
__global__ __launch_bounds__(256) void k_bucket(const int* __restrict__ il,
                                                uint_t* __restrict__ cur,
                                                uint_t* __restrict__ recs) {
    __shared__ uint_t cnt[NBKT], bas[NBKT];
    int t = threadIdx.x;
    for (int i = t; i < NBKT; i += 256) cnt[i] = 0u;
    __syncthreads();

    int base = blockIdx.x * 4096;
    uint_t myrec[16], mybl[16];
    #pragma unroll
    for (int i = 0; i < 16; ++i) {
        int p = base + i * 256 + t;
        myrec[i] = 0xFFFFFFFFu;
        if (p < NNZ_C) {
            uint_t n = (uint_t)il[p];
            uint_t e = (uint_t)il[NNZ_C + p];
            uint_t bkt = e / BEDG;
            uint_t el  = e - bkt * BEDG;
            uint_t slot = atomicAdd(&cnt[bkt], 1u);
            myrec[i] = (n << 7) | el;            // el < 125 fits 7 bits
            mybl[i]  = (bkt << 16) | slot;
        }
    }
    __syncthreads();
    for (int i = t; i < NBKT; i += 256) bas[i] = cnt[i] ? atomicAdd(&cur[i], cnt[i]) : 0u;
    __syncthreads();
    #pragma unroll
    for (int i = 0; i < 16; ++i) {
        if (myrec[i] != 0xFFFFFFFFu) {
            uint_t bkt = mybl[i] >> 16, slot = mybl[i] & 0xFFFFu;
            uint_t pos = bas[bkt] + slot;
            if (pos < RCAP) recs[(size_t)bkt * RCAP + pos] = myrec[i];
        }
    }
}

// ---- K4b: per-bucket LDS accumulation, fp16 gather (L2-resident) ------------
__global__ __launch_bounds__(512) void k_scan(const uint_t* __restrict__ recs,
                                              const uint_t* __restrict__ cur,
                                              const __half* __restrict__ nZh,
                                              float* __restrict__ S,
                                              uint_t* __restrict__ cntE) {
    __shared__ __align__(16) float Ss[BEDG * KD];   // 8 KB
    __shared__ uint_t Ce[BEDG];
    int t = threadIdx.x;
    int bkt = blockIdx.x >> 2, s = blockIdx.x & 3;

    for (int i = t; i < BEDG * KD / 4; i += 512)
        ((float4*)Ss)[i] = make_float4(0.f, 0.f, 0.f, 0.f);
    if (t < BEDG) Ce[t] = 0u;
    __syncthreads();

    uint_t c = cur[bkt];
    if (c > RCAP) c = RCAP;
    uint_t lo = (c * (uint_t)s) >> 2, hi = (c * (uint_t)(s + 1)) >> 2;
    const uint_t* r = recs + (size_t)bkt * RCAP;
    int k = t & 15;
    bool lane0 = (k == 0);
    uint_t i = lo + (uint_t)(t >> 4);          // 32 groups per block

    for (; i + 96 < hi; i += 128) {
        uint_t rc0 = r[i], rc1 = r[i + 32], rc2 = r[i + 64], rc3 = r[i + 96];
        float v0 = __half2float(nZh[(size_t)(rc0 >> 7) * KD + k]);
        float v1 = __half2float(nZh[(size_t)(rc1 >> 7) * KD + k]);
        float v2 = __half2float(nZh[(size_t)(rc2 >> 7) * KD + k]);
        float v3 = __half2float(nZh[(size_t)(rc3 >> 7) * KD + k]);
        if (lane0) {
            atomicAdd(&Ce[rc0 & 127u], 1u);     // native ds_add_u32
            atomicAdd(&Ce[rc1 & 127u], 1u);
            atomicAdd(&Ce[rc2 & 127u], 1u);
            atomicAdd(&Ce[rc3 & 127u], 1u);
        }
        lds_fadd(&Ss[(rc0 & 127u) * KD + k], v0);
        lds_fadd(&Ss[(rc1 & 127u) * KD + k], v1);
        lds_fadd(&Ss[(rc2 & 127u) * KD + k], v2);
        lds_fadd(&Ss[(rc3 & 127u) * KD + k], v3);
    }
    for (; i < hi; i += 32) {
        uint_t rc = r[i];
        float v = __half2float(nZh[(size_t)(rc >> 7) * KD + k]);
        if (lane0) atomicAdd(&Ce[rc & 127u], 1u);
        lds_fadd(&Ss[(rc & 127u) * KD + k], v);
    }
    __syncthreads();

    // flush tile -> global (contiguous coalesced atomics)
    float* gS = S + (size_t)bkt * (BEDG * KD);
    for (int j = t; j < BEDG * KD; j += 512)
        atomicAdd(&gS[j], Ss[j]);
    if (t < BEDG) {
        uint_t cv = Ce[t];
        if (cv) atomicAdd(&cntE[bkt * BEDG + t], cv);
    }
}

// ---- K4c: theta[k] = sum_e S[e,k]^2 / De[e] ---------------------------------
__global__ __launch_bounds__(256) void k_theta(const float* __restrict__ S,
                                               const uint_t* __restrict__ cntE,
                                               float* __restrict__ acc) {
    __shared__ float sacc[KD];
    int t = threadIdx.x;
    if (t < KD) sacc[t] = 0.f;
    __syncthreads();
    int e = blockIdx.x * 256 + t;
    if (e < NE_C) {
        float rinv = 1.f / fmaxf((float)cntE[e], EPSF);
        const float4* s4 = (const float4*)(S + (size_t)e * KD);
        #pragma unroll
        for (int i = 0; i < 4; ++i) {
            float4 s = s4[i];
            lds_fadd(&sacc[4*i+0], s.x * s.x * rinv);
            lds_fadd(&sacc[4*i+1], s.y * s.y * rinv);
            lds_fadd(&sacc[4*i+2], s.z * s.z * rinv);
            lds_fadd(&sacc[4*i+3], s.w * s.w * rinv);
        }
    }
    __syncthreads();
    if (t < KD) atomicAdd(&acc[t], sacc[t]);
}

// ---- K5: finalize ------------------------------------------------------------
__global__ void k_final(const float* __restrict__ acc, float* __restrict__ out) {
    if (blockIdx.x == 0 && threadIdx.x == 0) {
        float rsum = 0.f;
        #pragma unroll
        for (int k = 0; k < KD; ++k) {
            float theta = acc[k];
            float fd    = fmaxf(acc[16 + k], EPSF);
            float rq    = 1.f - theta / fd;
            if (!isfinite(rq)) rq = 0.f;
            rsum += rq;
        }
        float rl = rsum / (float)KD;
        float pS = acc[32], nS = acc[33], pC = acc[34], nC = acc[35];
        float pm = pS / fmaxf(pC, 1.f);
        float nm = nS / fmaxf(nC, 1.f);
        float sep = fabsf(pm - nm);
        float pen = (pC == 0.f || nC == 0.f) ? 1.f : 1.f / (sep + EPSF);
        out[0] = rl + LSEP * pen;
    }
}

extern "C" void kernel_launch(void* const* d_in, const int* in_sizes, int n_in,
                              void* d_out, int out_size, void* d_ws, size_t ws_size,
                              hipStream_t stream) {
    const float* Z  = (const float*)d_in[0];
    const int*   il = (const int*)d_in[1];   // (2, NNZ) int32
    float*  ws     = (float*)d_ws;
    uint_t* packed = (uint_t*)d_ws + W_PK;
    uint_t* cur    = (uint_t*)d_ws + W_CUR;
    float*  acc    = ws + W_ACC;
    uint_t* cntE   = (uint_t*)d_ws + W_CNTE;
    float*  S      = ws + W_S;
    float*  Dv     = ws + W_DV;
    __half* nZh    = (__half*)(ws + W_NZ);
    uint_t* recs   = (uint_t*)d_ws + W_REC;
    float*  out    = (float*)d_out;

    // zero packed + cursors + acc + cntE + S (rest fully overwritten)
    hipMemsetAsync(ws, 0, (size_t)W_ZERO * sizeof(float), stream);

    k_hist  <<<128, 512, 0, stream>>>(il, packed);
    k_unpack<<<(25000 + 255) / 256, 256, 0, stream>>>(packed, Dv);
    k_norm  <<<(NN_C + 255) / 256, 256, 0, stream>>>(Z, Dv, nZh, acc);
    k_bucket<<<(NNZ_C + 4095) / 4096, 256, 0, stream>>>(il, cur, recs);
    k_scan  <<<NBKT * SLICES, 512, 0, stream>>>(recs, cur, nZh, S, cntE);
    k_theta <<<(NE_C + 255) / 256, 256, 0, stream>>>(S, cntE, acc);
    k_final <<<1, 64, 0, stream>>>(acc, out);
}